// Round 1
// baseline (407.035 us; speedup 1.0000x reference)
//
#include <hip/hip_runtime.h>
#include <cstdint>
#include <math.h>

#define SCAN_BLOCKS 1024
#define BLOCK 256

__device__ __forceinline__ uint32_t f2key(float f) {
    uint32_t u = __float_as_uint(f);
    return (u & 0x80000000u) ? ~u : (u | 0x80000000u);
}
__device__ __forceinline__ float key2f(uint32_t k) {
    uint32_t u = (k & 0x80000000u) ? (k ^ 0x80000000u) : ~k;
    return __uint_as_float(u);
}

// ---- tiny kernel: compute the 8 ranks (lo, lo+1 for quantiles j=1..4) ----
__global__ void rank_init_k(uint32_t* rem0, int N) {
    if (blockIdx.x == 0 && threadIdx.x == 0) {
        for (int r = 0; r < 8; ++r) {
            int j = r / 2 + 1;
            double pos = (double)(N - 1) * (double)j / 5.0;
            uint32_t lo = (uint32_t)pos;  // floor (pos >= 0)
            rem0[r] = lo + (r & 1);
        }
    }
}

// ---- pass A: 4096-bin histogram of top 12 bits of sortable key ----
__global__ void histA_k(const float* __restrict__ t, int N, uint32_t* __restrict__ hist1) {
    __shared__ uint32_t h[4096];
    for (int i = threadIdx.x; i < 4096; i += BLOCK) h[i] = 0;
    __syncthreads();
    int n4 = N >> 2;
    const float4* t4 = (const float4*)t;
    for (int i = blockIdx.x * BLOCK + threadIdx.x; i < n4; i += gridDim.x * BLOCK) {
        float4 v = t4[i];
        atomicAdd(&h[f2key(v.x) >> 20], 1u);
        atomicAdd(&h[f2key(v.y) >> 20], 1u);
        atomicAdd(&h[f2key(v.z) >> 20], 1u);
        atomicAdd(&h[f2key(v.w) >> 20], 1u);
    }
    if (blockIdx.x == 0 && threadIdx.x == 0) {
        for (int i = n4 << 2; i < N; ++i) atomicAdd(&h[f2key(t[i]) >> 20], 1u);
    }
    __syncthreads();
    for (int i = threadIdx.x; i < 4096; i += BLOCK) {
        uint32_t v = h[i];
        if (v) atomicAdd(&hist1[i], v);
    }
}

// ---- generic rank-select within a histogram; one block per rank ----
template <int NBINS>
__global__ void select_k(const uint32_t* __restrict__ hist, int stride,
                         const uint32_t* __restrict__ rank_in,
                         uint32_t* __restrict__ bucket_out,
                         uint32_t* __restrict__ rem_out) {
    constexpr int BPT = NBINS / BLOCK;
    __shared__ uint32_t scan[BLOCK];
    const uint32_t* h = hist + (size_t)blockIdx.x * (size_t)stride;
    uint32_t rank = rank_in[blockIdx.x];
    uint32_t local[BPT];
    uint32_t s = 0;
    int t = threadIdx.x;
#pragma unroll
    for (int i = 0; i < BPT; ++i) { local[i] = h[t * BPT + i]; s += local[i]; }
    scan[t] = s;
    __syncthreads();
    for (int off = 1; off < BLOCK; off <<= 1) {
        uint32_t v = (t >= off) ? scan[t - off] : 0u;
        __syncthreads();
        scan[t] += v;
        __syncthreads();
    }
    uint32_t cum = scan[t] - s;  // exclusive prefix
#pragma unroll
    for (int i = 0; i < BPT; ++i) {
        uint32_t c = local[i];
        if (rank >= cum && rank < cum + c) {
            bucket_out[blockIdx.x] = (uint32_t)(t * BPT + i);
            rem_out[blockIdx.x] = rank - cum;
        }
        cum += c;
    }
}

// ---- pass B: per-rank 1024-bin histograms of bits [10,20) within rank's top bucket ----
__global__ void histB_k(const float* __restrict__ t, int N,
                        const uint32_t* __restrict__ bucket1,
                        uint32_t* __restrict__ hist2) {
    __shared__ uint32_t h[8192];
    for (int i = threadIdx.x; i < 8192; i += BLOCK) h[i] = 0;
    uint32_t b[8];
#pragma unroll
    for (int r = 0; r < 8; ++r) b[r] = bucket1[r];
    __syncthreads();
    int n4 = N >> 2;
    const float4* t4 = (const float4*)t;
    for (int i = blockIdx.x * BLOCK + threadIdx.x; i < n4; i += gridDim.x * BLOCK) {
        float4 v = t4[i];
        float vals[4] = {v.x, v.y, v.z, v.w};
#pragma unroll
        for (int c = 0; c < 4; ++c) {
            uint32_t key = f2key(vals[c]);
            uint32_t top = key >> 20, mid = (key >> 10) & 1023u;
#pragma unroll
            for (int r = 0; r < 8; ++r)
                if (top == b[r]) atomicAdd(&h[r * 1024 + mid], 1u);
        }
    }
    if (blockIdx.x == 0 && threadIdx.x == 0) {
        for (int i = n4 << 2; i < N; ++i) {
            uint32_t key = f2key(t[i]);
            uint32_t top = key >> 20, mid = (key >> 10) & 1023u;
            for (int r = 0; r < 8; ++r)
                if (top == b[r]) atomicAdd(&h[r * 1024 + mid], 1u);
        }
    }
    __syncthreads();
    for (int i = threadIdx.x; i < 8192; i += BLOCK) {
        uint32_t v = h[i];
        if (v) atomicAdd(&hist2[i], v);
    }
}

// ---- pass C: per-rank 1024-bin histograms of low 10 bits within rank's 22-bit prefix ----
__global__ void histC_k(const float* __restrict__ t, int N,
                        const uint32_t* __restrict__ bucket1,
                        const uint32_t* __restrict__ bucket2,
                        uint32_t* __restrict__ hist3) {
    __shared__ uint32_t h[8192];
    for (int i = threadIdx.x; i < 8192; i += BLOCK) h[i] = 0;
    uint32_t pref[8];
#pragma unroll
    for (int r = 0; r < 8; ++r) pref[r] = (bucket1[r] << 10) | bucket2[r];
    __syncthreads();
    int n4 = N >> 2;
    const float4* t4 = (const float4*)t;
    for (int i = blockIdx.x * BLOCK + threadIdx.x; i < n4; i += gridDim.x * BLOCK) {
        float4 v = t4[i];
        float vals[4] = {v.x, v.y, v.z, v.w};
#pragma unroll
        for (int c = 0; c < 4; ++c) {
            uint32_t key = f2key(vals[c]);
            uint32_t p22 = key >> 10, low = key & 1023u;
#pragma unroll
            for (int r = 0; r < 8; ++r)
                if (p22 == pref[r]) atomicAdd(&h[r * 1024 + low], 1u);
        }
    }
    if (blockIdx.x == 0 && threadIdx.x == 0) {
        for (int i = n4 << 2; i < N; ++i) {
            uint32_t key = f2key(t[i]);
            uint32_t p22 = key >> 10, low = key & 1023u;
            for (int r = 0; r < 8; ++r)
                if (p22 == pref[r]) atomicAdd(&h[r * 1024 + low], 1u);
        }
    }
    __syncthreads();
    for (int i = threadIdx.x; i < 8192; i += BLOCK) {
        uint32_t v = h[i];
        if (v) atomicAdd(&hist3[i], v);
    }
}

// ---- final: reconstruct quantiles, fused label+weight+MSE reduce ----
__global__ void final_k(const float* __restrict__ p, const float* __restrict__ t, int N,
                        const uint32_t* __restrict__ b1, const uint32_t* __restrict__ b2,
                        const uint32_t* __restrict__ b3, float* __restrict__ out) {
    float q1, q2, q3, q4;
    {
        float v[8];
#pragma unroll
        for (int r = 0; r < 8; ++r) {
            uint32_t key = (b1[r] << 20) | (b2[r] << 10) | b3[r];
            v[r] = key2f(key);
        }
        float q[4];
#pragma unroll
        for (int j = 1; j <= 4; ++j) {
            double pos = (double)(N - 1) * (double)j / 5.0;
            double frac = pos - floor(pos);
            q[j - 1] = (float)((double)v[2 * (j - 1)] +
                               frac * ((double)v[2 * j - 1] - (double)v[2 * (j - 1)]));
        }
        q1 = q[0]; q2 = q[1]; q3 = q[2]; q4 = q[3];
    }
    int n4 = N >> 2;
    const float4* p4 = (const float4*)p;
    const float4* t4 = (const float4*)t;
    float acc = 0.f;
    for (int i = blockIdx.x * BLOCK + threadIdx.x; i < n4; i += gridDim.x * BLOCK) {
        float4 pv = p4[i], tv = t4[i];
        float pp[4] = {pv.x, pv.y, pv.z, pv.w};
        float tt[4] = {tv.x, tv.y, tv.z, tv.w};
#pragma unroll
        for (int c = 0; c < 4; ++c) {
            float tvv = tt[c];
            int idx = (int)(tvv > q1) + (int)(tvv > q2) + (int)(tvv > q3) + (int)(tvv > q4);
            float w = fabsf(3.0f - (float)idx) * 0.33333334f;
            float d = pp[c] - tvv;
            acc += w * d * d;
        }
    }
    if (blockIdx.x == 0 && threadIdx.x == 0) {
        for (int i = n4 << 2; i < N; ++i) {
            float tvv = t[i];
            int idx = (int)(tvv > q1) + (int)(tvv > q2) + (int)(tvv > q3) + (int)(tvv > q4);
            float w = fabsf(3.0f - (float)idx) * 0.33333334f;
            float d = p[i] - tvv;
            acc += w * d * d;
        }
    }
    // wave + block reduction, then one atomic per block
    for (int off = 32; off > 0; off >>= 1) acc += __shfl_down(acc, off, 64);
    __shared__ float wsum[BLOCK / 64];
    int lane = threadIdx.x & 63, wv = threadIdx.x >> 6;
    if (lane == 0) wsum[wv] = acc;
    __syncthreads();
    if (threadIdx.x == 0) {
        float s = 0.f;
#pragma unroll
        for (int i = 0; i < BLOCK / 64; ++i) s += wsum[i];
        float inv_n = (float)(1.0 / (double)N);
        atomicAdd(out, s * inv_n);
    }
}

extern "C" void kernel_launch(void* const* d_in, const int* in_sizes, int n_in,
                              void* d_out, int out_size, void* d_ws, size_t ws_size,
                              hipStream_t stream) {
    const float* pred = (const float*)d_in[0];
    const float* targ = (const float*)d_in[1];
    int N = in_sizes[1];
    uint32_t* ws = (uint32_t*)d_ws;
    uint32_t* hist1 = ws;           // 4096
    uint32_t* hist2 = ws + 4096;    // 8192
    uint32_t* hist3 = ws + 12288;   // 8192
    uint32_t* rem0 = ws + 20480;    // 8
    uint32_t* b1 = ws + 20488;      // 8
    uint32_t* rem1 = ws + 20496;    // 8
    uint32_t* b2 = ws + 20504;      // 8
    uint32_t* rem2 = ws + 20512;    // 8
    uint32_t* b3 = ws + 20520;      // 8
    uint32_t* rem3 = ws + 20528;    // 8
    float* out = (float*)d_out;

    hipMemsetAsync(ws, 0, 20480 * sizeof(uint32_t), stream);  // hists only
    hipMemsetAsync(d_out, 0, sizeof(float), stream);
    rank_init_k<<<1, 1, 0, stream>>>(rem0, N);
    histA_k<<<SCAN_BLOCKS, BLOCK, 0, stream>>>(targ, N, hist1);
    select_k<4096><<<8, BLOCK, 0, stream>>>(hist1, 0, rem0, b1, rem1);
    histB_k<<<SCAN_BLOCKS, BLOCK, 0, stream>>>(targ, N, b1, hist2);
    select_k<1024><<<8, BLOCK, 0, stream>>>(hist2, 1024, rem1, b2, rem2);
    histC_k<<<SCAN_BLOCKS, BLOCK, 0, stream>>>(targ, N, b1, b2, hist3);
    select_k<1024><<<8, BLOCK, 0, stream>>>(hist3, 1024, rem2, b3, rem3);
    final_k<<<SCAN_BLOCKS, BLOCK, 0, stream>>>(pred, targ, N, b1, b2, b3, out);
}